// Round 1
// baseline (237.310 us; speedup 1.0000x reference)
//
#include <hip/hip_runtime.h>
#include <stdint.h>

// Shapes (fixed by the problem)
#define Bn 256
#define Un 128
#define Pn 64
#define Hn 768
#define Ototal 192   // 128 row-logit outputs + 64 col-logit outputs
#define KC 16        // split-K chunks in phase B (K=8192 -> 512 each)

#define LDB 72       // phaseB LDS row stride (ushorts): 144B = 9*16 (b128-aligned)

typedef short s4v __attribute__((ext_vector_type(4)));
typedef short s8v __attribute__((ext_vector_type(8)));
typedef float f4v __attribute__((ext_vector_type(4)));

__device__ __forceinline__ short f2bf(float x) {
  union { float f; uint32_t u; } c; c.f = x;
  uint32_t r = (c.u + 0x7fffu + ((c.u >> 16) & 1u)) >> 16;  // RNE
  return (short)(r & 0xffffu);
}

__device__ __forceinline__ float dot4(float4 v) {
  return v.x * v.x + v.y * v.y + v.z * v.z + v.w * v.w;
}

__device__ __forceinline__ s8v pack8(float4 x, float4 y) {
  s8v r;
  r[0] = f2bf(x.x); r[1] = f2bf(x.y); r[2] = f2bf(x.z); r[3] = f2bf(x.w);
  r[4] = f2bf(y.x); r[5] = f2bf(y.y); r[6] = f2bf(y.z); r[7] = f2bf(y.w);
  return r;
}

// ---------------------------------------------------------------------------
// Kernel 1: pack weights into bf16 W'[o][k], o<128: w_utt[o,i,j]; o>=128:
// w_pheno[o-128, j, i]  (k = i*64 + j) so both logit einsums share one GEMM.
// ---------------------------------------------------------------------------
__global__ void __launch_bounds__(256) convW(const float* __restrict__ w_utt,
                                             const float* __restrict__ w_ph,
                                             ushort* __restrict__ Wbf) {
  __shared__ float tile[64 * 129];   // [j][i], +1 pad -> conflict-free columns
  const int bx = blockIdx.x;
  const int t = threadIdx.x;
  if (bx < 4096) {
    int idx = bx * 256 + t;                       // 0 .. 128*8192-1
    Wbf[idx] = (ushort)f2bf(w_utt[idx]);
    return;
  }
  const int oc = bx - 4096;                       // 0..63
  const float* src = w_ph + (size_t)oc * 8192;    // [j][i] = 64 x 128
#pragma unroll
  for (int itr = 0; itr < 8; ++itr) {
    int idx = itr * 1024 + t * 4;                 // 4 consecutive i of one j-row
    int j = idx >> 7, i = idx & 127;
    float4 v = *(const float4*)(src + idx);       // coalesced 16B
    tile[j * 129 + i + 0] = v.x;
    tile[j * 129 + i + 1] = v.y;
    tile[j * 129 + i + 2] = v.z;
    tile[j * 129 + i + 3] = v.w;
  }
  __syncthreads();
  const size_t obase = (size_t)(128 + oc) * 8192;
#pragma unroll
  for (int itr = 0; itr < 8; ++itr) {
    int k = itr * 1024 + t * 4;                   // k = i*64 + j
    int i = k >> 6, j = k & 63;
    s4v o4 = { f2bf(tile[(j + 0) * 129 + i]),
               f2bf(tile[(j + 1) * 129 + i]),
               f2bf(tile[(j + 2) * 129 + i]),
               f2bf(tile[(j + 3) * 129 + i]) };
    *(s4v*)&Wbf[obase + k] = o4;                  // coalesced 8B
  }
}

// ---------------------------------------------------------------------------
// Kernel 2 (REWRITTEN): cosine-sim matrix, reg-direct MFMA fragments.
// No LDS, no barriers: each wave loads its A fragment (16 u-rows x 32 k f32)
// and all four B fragments (64 p-rows x 32 k) straight from global, converts
// to bf16 in registers, and MFMAs. Counted vmcnt waits (no barrier drains)
// keep ~20 loads in flight per wave. Norm sums-of-squares computed per-lane
// on the f32 data, reduced with shfl_xor(16/32).
// Grid 512 = (half<<8)|b so the two blocks sharing batch b's p-rows land on
// the same XCD (256 % 8 == 0) for L2 reuse.
// ---------------------------------------------------------------------------
__global__ void __launch_bounds__(256) phaseA(const float* __restrict__ utt,
                                              const float* __restrict__ ph,
                                              ushort* __restrict__ Cbf) {
  const int bx = blockIdx.x;
  const int b = bx & 255;
  const int half = bx >> 8;
  const int t = threadIdx.x;          // 0..255
  const int w = t >> 6, l = t & 63;   // 4 waves, wave w owns u-rows w*16..+16
  const int m  = l & 15;              // fragment row within 16-row tile
  const int ko = (l >> 4) * 8;        // k offset within 32-wide chunk

  const size_t RS = (size_t)Bn * Hn;  // row stride in [len,B,H] layout

  const float* ua  = utt + (size_t)(half * 64 + w * 16 + m) * RS
                         + (size_t)b * Hn + ko;
  const float* pa0 = ph  + (size_t)m * RS + (size_t)b * Hn + ko;
  const float* pa1 = pa0 + (size_t)16 * RS;
  const float* pa2 = pa0 + (size_t)32 * RS;
  const float* pa3 = pa0 + (size_t)48 * RS;

  f4v zero4 = {0.f, 0.f, 0.f, 0.f};
  f4v acc0 = zero4, acc1 = zero4, acc2 = zero4, acc3 = zero4;
  float ssu = 0.f, ssp0 = 0.f, ssp1 = 0.f, ssp2 = 0.f, ssp3 = 0.f;

#pragma unroll 2
  for (int c = 0; c < 24; ++c) {
    const int o = c * 32;
    float4 a0  = *(const float4*)(ua  + o);
    float4 a1  = *(const float4*)(ua  + o + 4);
    float4 q00 = *(const float4*)(pa0 + o);
    float4 q01 = *(const float4*)(pa0 + o + 4);
    float4 q10 = *(const float4*)(pa1 + o);
    float4 q11 = *(const float4*)(pa1 + o + 4);
    float4 q20 = *(const float4*)(pa2 + o);
    float4 q21 = *(const float4*)(pa2 + o + 4);
    float4 q30 = *(const float4*)(pa3 + o);
    float4 q31 = *(const float4*)(pa3 + o + 4);

    ssu  += dot4(a0)  + dot4(a1);
    ssp0 += dot4(q00) + dot4(q01);
    ssp1 += dot4(q10) + dot4(q11);
    ssp2 += dot4(q20) + dot4(q21);
    ssp3 += dot4(q30) + dot4(q31);

    s8v af = pack8(a0, a1);
    acc0 = __builtin_amdgcn_mfma_f32_16x16x32_bf16(af, pack8(q00, q01), acc0, 0, 0, 0);
    acc1 = __builtin_amdgcn_mfma_f32_16x16x32_bf16(af, pack8(q10, q11), acc1, 0, 0, 0);
    acc2 = __builtin_amdgcn_mfma_f32_16x16x32_bf16(af, pack8(q20, q21), acc2, 0, 0, 0);
    acc3 = __builtin_amdgcn_mfma_f32_16x16x32_bf16(af, pack8(q30, q31), acc3, 0, 0, 0);
  }

  // Reduce sumsq across the 4 k-slice lane groups: lanes {x, x^16, x^32, x^48}
  // hold the same row. After this, lane l holds the full sumsq for:
  //   u-row (w*16 + m)  in ssu;  p-row (jt*16 + m) in ssp{jt}.
  ssu  += __shfl_xor(ssu, 16);  ssu  += __shfl_xor(ssu, 32);
  ssp0 += __shfl_xor(ssp0, 16); ssp0 += __shfl_xor(ssp0, 32);
  ssp1 += __shfl_xor(ssp1, 16); ssp1 += __shfl_xor(ssp1, 32);
  ssp2 += __shfl_xor(ssp2, 16); ssp2 += __shfl_xor(ssp2, 32);
  ssp3 += __shfl_xor(ssp3, 16); ssp3 += __shfl_xor(ssp3, 32);

  const float ip0 = 1.f / fmaxf(sqrtf(ssp0), 1e-8f);
  const float ip1 = 1.f / fmaxf(sqrtf(ssp1), 1e-8f);
  const float ip2 = 1.f / fmaxf(sqrtf(ssp2), 1e-8f);
  const float ip3 = 1.f / fmaxf(sqrtf(ssp3), 1e-8f);

  // D layout (verified): col = lane&15, row = (lane>>4)*4 + reg
  const int rq = (l >> 4) * 4;
  float inu[4];
#pragma unroll
  for (int r = 0; r < 4; ++r) {
    float su = __shfl(ssu, rq + r);   // lane (rq+r) holds tile-row rq+r
    inu[r] = 1.f / fmaxf(sqrtf(su), 1e-8f);
  }

  const size_t cbase = ((size_t)b * Un + half * 64 + w * 16) * Pn;
#pragma unroll
  for (int r = 0; r < 4; ++r) {
    int row = rq + r;
    Cbf[cbase + (size_t)row * Pn +  0 + m] = (ushort)f2bf(acc0[r] * inu[r] * ip0);
    Cbf[cbase + (size_t)row * Pn + 16 + m] = (ushort)f2bf(acc1[r] * inu[r] * ip1);
    Cbf[cbase + (size_t)row * Pn + 32 + m] = (ushort)f2bf(acc2[r] * inu[r] * ip2);
    Cbf[cbase + (size_t)row * Pn + 48 + m] = (ushort)f2bf(acc3[r] * inu[r] * ip3);
  }
}

// ---------------------------------------------------------------------------
// Kernel 3: logits GEMM, M=256, N=192, K=8192, split-K (KC=16).
// ---------------------------------------------------------------------------
__global__ void __launch_bounds__(256) phaseB(const ushort* __restrict__ Cbf,
                                              const ushort* __restrict__ Wbf,
                                              float* __restrict__ partial) {
  const int kc = blockIdx.x;
  const int mt = blockIdx.y;
  const int nt = blockIdx.z;
  const int t = threadIdx.x;
  const int w = t >> 6, l = t & 63;

  __shared__ short Ab[64 * LDB];
  __shared__ short Bb[64 * LDB];

  const int row = t >> 2;          // 0..63
  const int k16 = (t & 3) * 16;    // 16 elems per thread per stage-row

  f4v zero4 = {0.f, 0.f, 0.f, 0.f};
  f4v acc[4] = {zero4, zero4, zero4, zero4};

  const ushort* Ag = Cbf + (size_t)(mt * 64 + row) * 8192 + kc * 512 + k16;
  const ushort* Bg = Wbf + (size_t)(nt * 64 + row) * 8192 + kc * 512 + k16;
  const int m  = l & 15;
  const int ko = (l >> 4) * 8;

  for (int c = 0; c < 8; ++c) {
    s8v av0 = *(const s8v*)(Ag + c * 64);
    s8v av1 = *(const s8v*)(Ag + c * 64 + 8);
    s8v bv0 = *(const s8v*)(Bg + c * 64);
    s8v bv1 = *(const s8v*)(Bg + c * 64 + 8);
    __syncthreads();
    *(s8v*)&Ab[row * LDB + k16]     = av0;
    *(s8v*)&Ab[row * LDB + k16 + 8] = av1;
    *(s8v*)&Bb[row * LDB + k16]     = bv0;
    *(s8v*)&Bb[row * LDB + k16 + 8] = bv1;
    __syncthreads();
#pragma unroll
    for (int ks = 0; ks < 2; ++ks) {
      s8v af = *(const s8v*)&Ab[(16 * w + m) * LDB + ks * 32 + ko];
#pragma unroll
      for (int jt = 0; jt < 4; ++jt) {
        s8v bf = *(const s8v*)&Bb[(16 * jt + m) * LDB + ks * 32 + ko];
        acc[jt] = __builtin_amdgcn_mfma_f32_16x16x32_bf16(af, bf, acc[jt], 0, 0, 0);
      }
    }
  }

  const int rq = (l >> 4) * 4;
#pragma unroll
  for (int jt = 0; jt < 4; ++jt) {
    int og = nt * 64 + 16 * jt + (l & 15);
#pragma unroll
    for (int r = 0; r < 4; ++r) {
      int bg = mt * 64 + 16 * w + rq + r;
      partial[((size_t)kc * Bn + bg) * Ototal + og] = acc[jt][r];
    }
  }
}

// ---------------------------------------------------------------------------
// Kernel 4: reduce split-K partials + bias + dual-group softmax.
// ---------------------------------------------------------------------------
__global__ void __launch_bounds__(192) phaseC(const float* __restrict__ partial,
                                              const float* __restrict__ b_utt,
                                              const float* __restrict__ b_ph,
                                              float* __restrict__ out) {
  const int b = blockIdx.x;
  const int t = threadIdx.x;      // 0..191
  const int w = t >> 6, l = t & 63;

  float v = 0.f;
#pragma unroll
  for (int kc = 0; kc < KC; ++kc)
    v += partial[((size_t)kc * Bn + b) * Ototal + t];
  v += (t < Un) ? b_utt[t] : b_ph[t - Un];

  __shared__ float red[3];
  float mx = v;
  for (int o = 32; o >= 1; o >>= 1) mx = fmaxf(mx, __shfl_xor(mx, o));
  if (l == 0) red[w] = mx;
  __syncthreads();
  float gmax = (t < Un) ? fmaxf(red[0], red[1]) : red[2];
  float e = expf(v - gmax);
  float s = e;
  for (int o = 32; o >= 1; o >>= 1) s += __shfl_xor(s, o);
  __syncthreads();
  if (l == 0) red[w] = s;
  __syncthreads();
  float gs = (t < Un) ? (red[0] + red[1]) : red[2];
  float r = e / gs;
  if (t < Un) out[(size_t)b * Un + t] = r;
  else        out[(size_t)Bn * Un + (size_t)b * Pn + (t - Un)] = r;
}

// ---------------------------------------------------------------------------
extern "C" void kernel_launch(void* const* d_in, const int* in_sizes, int n_in,
                              void* d_out, int out_size, void* d_ws, size_t ws_size,
                              hipStream_t stream) {
  const float* utt   = (const float*)d_in[0];  // [128,256,768]
  const float* ph    = (const float*)d_in[1];  // [64,256,768]
  const float* w_utt = (const float*)d_in[2];  // [128,128,64]
  const float* b_utt = (const float*)d_in[3];  // [128]
  const float* w_ph  = (const float*)d_in[4];  // [64,64,128]
  const float* b_ph  = (const float*)d_in[5];  // [64]

  char* ws = (char*)d_ws;
  ushort* Cbf     = (ushort*)(ws);                 // 256*128*64*2  = 4 MiB
  ushort* Wbf     = (ushort*)(ws + 4194304);       // 192*8192*2   = 3 MiB
  float*  partial = (float*)(ws + 7340032);        // 16*256*192*4 = 3 MiB

  convW <<<dim3(4096 + 64), dim3(256), 0, stream>>>(w_utt, w_ph, Wbf);
  phaseA<<<dim3(2 * Bn), dim3(256), 0, stream>>>(utt, ph, Cbf);
  phaseB<<<dim3(KC, 4, 3), dim3(256), 0, stream>>>(Cbf, Wbf, partial);
  phaseC<<<dim3(Bn), dim3(192), 0, stream>>>(partial, b_utt, b_ph, (float*)d_out);
}

// Round 2
// 208.039 us; speedup vs baseline: 1.1407x; 1.1407x over previous
//
#include <hip/hip_runtime.h>
#include <stdint.h>

// Shapes (fixed by the problem)
#define Bn 256
#define Un 128
#define Pn 64
#define Hn 768
#define Ototal 192   // 128 row-logit outputs + 64 col-logit outputs
#define KC 16        // split-K chunks in phase B (K=8192 -> 512 each)

#define LDU 40       // phaseA LDS row stride (ushorts): 80B = 5*16 (b128-aligned)
#define LDB 72       // phaseB LDS row stride (ushorts): 144B = 9*16 (b128-aligned)

typedef short s4v __attribute__((ext_vector_type(4)));
typedef short s8v __attribute__((ext_vector_type(8)));
typedef float f4v __attribute__((ext_vector_type(4)));

__device__ __forceinline__ short f2bf(float x) {
  union { float f; uint32_t u; } c; c.f = x;
  uint32_t r = (c.u + 0x7fffu + ((c.u >> 16) & 1u)) >> 16;  // RNE
  return (short)(r & 0xffffu);
}

__device__ __forceinline__ float dot4(float4 v) {
  return v.x * v.x + v.y * v.y + v.z * v.z + v.w * v.w;
}

// ---------------------------------------------------------------------------
// Fused kernel: phaseA (cosine-sim matrix, blocks 0..511) + convW (weight
// pack, blocks 512..2623). The two paths are fully independent (convW output
// is consumed only by phaseB), so fusing them saves one launch + gap.
//
// phaseA (blocks 0..511, 2 blocks/batch): round-0 verified LDS+MFMA
// structure, now DOUBLE-BUFFERED: one __syncthreads per chunk (24 barrier
// drains instead of 48), next-chunk prefetch issued at loop top so it is in
// flight across ds_read+MFMA and only waited at the convert (counted vmcnt
// from the register dependency; the barrier drain is then nearly free).
// ---------------------------------------------------------------------------
__global__ void __launch_bounds__(512) phaseAW(const float* __restrict__ utt,
                                               const float* __restrict__ ph,
                                               ushort* __restrict__ Cbf,
                                               const float* __restrict__ w_utt,
                                               const float* __restrict__ w_ph,
                                               ushort* __restrict__ Wbf) {
  __shared__ __align__(16) float smemf[64 * 129];   // 33024 B, aliased below
  char* smem = (char*)smemf;
  const int bx = blockIdx.x;
  const int t = threadIdx.x;

  if (bx >= 512) {
    if (bx < 2560) {
      // w_utt convert: 2048 blocks x 512 thr x 1 elem -> W'[o][k]=w_utt[o,i,j]
      int idx = (bx - 512) * 512 + t;               // 0 .. 128*8192-1
      Wbf[idx] = (ushort)f2bf(w_utt[idx]);
      return;
    }
    // w_ph transpose: 64 blocks, W'[128+oc][i*64+j] = w_ph[oc,j,i]
    float* tile = smemf;                            // [j][i] 64 x 129 (+1 pad)
    const int oc = bx - 2560;
    const float* src = w_ph + (size_t)oc * 8192;    // [j][i] = 64 x 128
#pragma unroll
    for (int itr = 0; itr < 4; ++itr) {
      int idx = itr * 2048 + t * 4;                 // 4 consecutive i of one j
      int j = idx >> 7, i = idx & 127;
      float4 v = *(const float4*)(src + idx);       // coalesced 16B
      tile[j * 129 + i + 0] = v.x;
      tile[j * 129 + i + 1] = v.y;
      tile[j * 129 + i + 2] = v.z;
      tile[j * 129 + i + 3] = v.w;
    }
    __syncthreads();
    const size_t obase = (size_t)(128 + oc) * 8192;
#pragma unroll
    for (int itr = 0; itr < 4; ++itr) {
      int k = itr * 2048 + t * 4;                   // k = i*64 + j
      int i = k >> 6, j = k & 63;
      s4v o4 = { f2bf(tile[(j + 0) * 129 + i]),
                 f2bf(tile[(j + 1) * 129 + i]),
                 f2bf(tile[(j + 2) * 129 + i]),
                 f2bf(tile[(j + 3) * 129 + i]) };
      *(s4v*)&Wbf[obase + k] = o4;                  // coalesced 8B
    }
    return;
  }

  // ---- phaseA path (blocks 0..511) ----
  // LDS overlay: uA[2][64*LDU] (10240B) | pB[2][64*LDU] (10240B) | norms
  short (*uA)[64 * LDU] = (short (*)[64 * LDU])(smem);
  short (*pB)[64 * LDU] = (short (*)[64 * LDU])(smem + 10240);
  float* s_inu = (float*)(smem + 20480);
  float* s_inp = (float*)(smem + 20736);

  const int b = bx >> 1, half = bx & 1;
  const int w = t >> 6, l = t & 63;

  const int r  = t >> 3;              // 0..63 (row for both u-half and p)
  const int cc = (t & 7) * 4;         // col start within 32-float chunk

  const size_t rstride = (size_t)Bn * Hn;
  const float* ubase = utt + (size_t)b * Hn + (size_t)(half * 64 + r) * rstride + cc;
  const float* pbase = ph  + (size_t)b * Hn + (size_t)r * rstride + cc;

  const int m  = l & 15;
  const int ko = (l >> 4) * 8;
  const int it = w & 3;               // i-tile (16 rows), 0..3
  const int jp = w >> 2;              // j-half (32 cols), 0..1
  const int lw = r * LDU + (t & 7) * 4;        // LDS write offset (elements)
  const int fo = (it * 16 + m) * LDU + ko;     // A fragment read offset
  const int go = (jp * 32 + m) * LDU + ko;     // B fragment read offset

  f4v zero4 = {0.f, 0.f, 0.f, 0.f};
  f4v acc0 = zero4, acc1 = zero4;
  float ssu = 0.f, ssp = 0.f;

  // prologue: stage chunk 0 into buffer 0
  {
    float4 a  = *(const float4*)ubase;
    float4 p0 = *(const float4*)pbase;
    ssu += dot4(a); ssp += dot4(p0);
    s4v au = { f2bf(a.x),  f2bf(a.y),  f2bf(a.z),  f2bf(a.w)  };
    s4v pp = { f2bf(p0.x), f2bf(p0.y), f2bf(p0.z), f2bf(p0.w) };
    *(s4v*)&uA[0][lw] = au;
    *(s4v*)&pB[0][lw] = pp;
  }
  __syncthreads();

#pragma unroll 2
  for (int c = 0; c < 24; ++c) {
    const int cur = c & 1;
    float4 nu, np;
    if (c < 23) {                     // issue next-chunk loads FIRST: in
      nu = *(const float4*)(ubase + (c + 1) * 32);   // flight across MFMA
      np = *(const float4*)(pbase + (c + 1) * 32);
    }
    s8v af  = *(const s8v*)&uA[cur][fo];
    s8v bf0 = *(const s8v*)&pB[cur][go];
    s8v bf1 = *(const s8v*)&pB[cur][go + 16 * LDU];
    acc0 = __builtin_amdgcn_mfma_f32_16x16x32_bf16(af, bf0, acc0, 0, 0, 0);
    acc1 = __builtin_amdgcn_mfma_f32_16x16x32_bf16(af, bf1, acc1, 0, 0, 0);
    if (c < 23) {                     // convert (waits the loads) + stage into
      ssu += dot4(nu); ssp += dot4(np);              // the OTHER buffer
      s4v au = { f2bf(nu.x), f2bf(nu.y), f2bf(nu.z), f2bf(nu.w) };
      s4v pp = { f2bf(np.x), f2bf(np.y), f2bf(np.z), f2bf(np.w) };
      *(s4v*)&uA[cur ^ 1][lw] = au;
      *(s4v*)&pB[cur ^ 1][lw] = pp;
    }
    __syncthreads();                  // one barrier per chunk
  }

  // row sumsq reductions: 8 threads/row are adjacent lanes
  ssu += __shfl_xor(ssu, 4); ssu += __shfl_xor(ssu, 2); ssu += __shfl_xor(ssu, 1);
  ssp += __shfl_xor(ssp, 4); ssp += __shfl_xor(ssp, 2); ssp += __shfl_xor(ssp, 1);
  if ((t & 7) == 0) {
    s_inu[r] = 1.f / fmaxf(sqrtf(ssu), 1e-8f);
    s_inp[r] = 1.f / fmaxf(sqrtf(ssp), 1e-8f);
  }
  __syncthreads();

  // epilogue: scale, store bf16 C[b][half*64+i][j]
  // D layout (verified m89/m91): col = lane&15, row = (lane>>4)*4 + reg
  const int cl = l & 15;
  const int rq = (l >> 4) * 4;
#pragma unroll
  for (int jt = 0; jt < 2; ++jt) {
    int j = jp * 32 + jt * 16 + cl;
    float sj = s_inp[j];
    f4v a = (jt == 0) ? acc0 : acc1;
#pragma unroll
    for (int rr = 0; rr < 4; ++rr) {
      int il = it * 16 + rq + rr;     // local row 0..63
      float v = a[rr] * s_inu[il] * sj;
      Cbf[((size_t)b * Un + half * 64 + il) * Pn + j] = (ushort)f2bf(v);
    }
  }
}

// ---------------------------------------------------------------------------
// Kernel 3: logits GEMM, M=256, N=192, K=8192, split-K (KC=16).
// ---------------------------------------------------------------------------
__global__ void __launch_bounds__(256) phaseB(const ushort* __restrict__ Cbf,
                                              const ushort* __restrict__ Wbf,
                                              float* __restrict__ partial) {
  const int kc = blockIdx.x;
  const int mt = blockIdx.y;
  const int nt = blockIdx.z;
  const int t = threadIdx.x;
  const int w = t >> 6, l = t & 63;

  __shared__ short Ab[64 * LDB];
  __shared__ short Bb[64 * LDB];

  const int row = t >> 2;          // 0..63
  const int k16 = (t & 3) * 16;    // 16 elems per thread per stage-row

  f4v zero4 = {0.f, 0.f, 0.f, 0.f};
  f4v acc[4] = {zero4, zero4, zero4, zero4};

  const ushort* Ag = Cbf + (size_t)(mt * 64 + row) * 8192 + kc * 512 + k16;
  const ushort* Bg = Wbf + (size_t)(nt * 64 + row) * 8192 + kc * 512 + k16;
  const int m  = l & 15;
  const int ko = (l >> 4) * 8;

  for (int c = 0; c < 8; ++c) {
    s8v av0 = *(const s8v*)(Ag + c * 64);
    s8v av1 = *(const s8v*)(Ag + c * 64 + 8);
    s8v bv0 = *(const s8v*)(Bg + c * 64);
    s8v bv1 = *(const s8v*)(Bg + c * 64 + 8);
    __syncthreads();
    *(s8v*)&Ab[row * LDB + k16]     = av0;
    *(s8v*)&Ab[row * LDB + k16 + 8] = av1;
    *(s8v*)&Bb[row * LDB + k16]     = bv0;
    *(s8v*)&Bb[row * LDB + k16 + 8] = bv1;
    __syncthreads();
#pragma unroll
    for (int ks = 0; ks < 2; ++ks) {
      s8v af = *(const s8v*)&Ab[(16 * w + m) * LDB + ks * 32 + ko];
#pragma unroll
      for (int jt = 0; jt < 4; ++jt) {
        s8v bf = *(const s8v*)&Bb[(16 * jt + m) * LDB + ks * 32 + ko];
        acc[jt] = __builtin_amdgcn_mfma_f32_16x16x32_bf16(af, bf, acc[jt], 0, 0, 0);
      }
    }
  }

  const int rq = (l >> 4) * 4;
#pragma unroll
  for (int jt = 0; jt < 4; ++jt) {
    int og = nt * 64 + 16 * jt + (l & 15);
#pragma unroll
    for (int r = 0; r < 4; ++r) {
      int bg = mt * 64 + 16 * w + rq + r;
      partial[((size_t)kc * Bn + bg) * Ototal + og] = acc[jt][r];
    }
  }
}

// ---------------------------------------------------------------------------
// Kernel 4: reduce split-K partials + bias + dual-group softmax.
// ---------------------------------------------------------------------------
__global__ void __launch_bounds__(192) phaseC(const float* __restrict__ partial,
                                              const float* __restrict__ b_utt,
                                              const float* __restrict__ b_ph,
                                              float* __restrict__ out) {
  const int b = blockIdx.x;
  const int t = threadIdx.x;      // 0..191
  const int w = t >> 6, l = t & 63;

  float v = 0.f;
#pragma unroll
  for (int kc = 0; kc < KC; ++kc)
    v += partial[((size_t)kc * Bn + b) * Ototal + t];
  v += (t < Un) ? b_utt[t] : b_ph[t - Un];

  __shared__ float red[3];
  float mx = v;
  for (int o = 32; o >= 1; o >>= 1) mx = fmaxf(mx, __shfl_xor(mx, o));
  if (l == 0) red[w] = mx;
  __syncthreads();
  float gmax = (t < Un) ? fmaxf(red[0], red[1]) : red[2];
  float e = expf(v - gmax);
  float s = e;
  for (int o = 32; o >= 1; o >>= 1) s += __shfl_xor(s, o);
  __syncthreads();
  if (l == 0) red[w] = s;
  __syncthreads();
  float gs = (t < Un) ? (red[0] + red[1]) : red[2];
  float r = e / gs;
  if (t < Un) out[(size_t)b * Un + t] = r;
  else        out[(size_t)Bn * Un + (size_t)b * Pn + (t - Un)] = r;
}

// ---------------------------------------------------------------------------
extern "C" void kernel_launch(void* const* d_in, const int* in_sizes, int n_in,
                              void* d_out, int out_size, void* d_ws, size_t ws_size,
                              hipStream_t stream) {
  const float* utt   = (const float*)d_in[0];  // [128,256,768]
  const float* ph    = (const float*)d_in[1];  // [64,256,768]
  const float* w_utt = (const float*)d_in[2];  // [128,128,64]
  const float* b_utt = (const float*)d_in[3];  // [128]
  const float* w_ph  = (const float*)d_in[4];  // [64,64,128]
  const float* b_ph  = (const float*)d_in[5];  // [64]

  char* ws = (char*)d_ws;
  ushort* Cbf     = (ushort*)(ws);                 // 256*128*64*2  = 4 MiB
  ushort* Wbf     = (ushort*)(ws + 4194304);       // 192*8192*2   = 3 MiB
  float*  partial = (float*)(ws + 7340032);        // 16*256*192*4 = 3 MiB

  phaseAW<<<dim3(2624), dim3(512), 0, stream>>>(utt, ph, Cbf, w_utt, w_ph, Wbf);
  phaseB <<<dim3(KC, 4, 3), dim3(256), 0, stream>>>(Cbf, Wbf, partial);
  phaseC <<<dim3(Bn), dim3(192), 0, stream>>>(partial, b_utt, b_ph, (float*)d_out);
}